// Round 7
// baseline (867.059 us; speedup 1.0000x reference)
//
#include <hip/hip_runtime.h>

typedef __attribute__((ext_vector_type(8))) short short8;
typedef __attribute__((ext_vector_type(4))) float f32x4;
typedef __attribute__((ext_vector_type(2))) unsigned u32x2;
typedef __attribute__((ext_vector_type(4))) unsigned u32x4;

#define SCL2 0.18033688011112042f   /* 64^-0.5 * log2(e), folded into Q */

__device__ __forceinline__ unsigned pk2(float lo, float hi) {
  unsigned r;
  asm("v_cvt_pk_bf16_f32 %0, %1, %2" : "=v"(r) : "v"(lo), "v"(hi));
  return r;
}

__device__ __forceinline__ short8 pk8(float4 a, float4 b) {
  u32x4 u = { pk2(a.x, a.y), pk2(a.z, a.w), pk2(b.x, b.y), pk2(b.z, b.w) };
  return __builtin_bit_cast(short8, u);
}

__global__ __launch_bounds__(256, 3)   // 3 waves/EU -> ~170 unified regs/wave, no spill
void lattn(const float* __restrict__ Qg, const float* __restrict__ Kg,
           const float* __restrict__ Vg, float* __restrict__ Og) {
  constexpr int S = 8192, H = 16, RS = H * 64;   // row stride in floats
  __shared__ __align__(16) unsigned char smem[49152];
  // double-buffered K/V tiles: [par][K 8KB | V 8KB], then per-wave P (4 KB each)
  unsigned char* Kb0 = smem;
  unsigned char* Vb0 = smem + 8192;
  unsigned char* Kb1 = smem + 16384;
  unsigned char* Vb1 = smem + 24576;

  const int tid = threadIdx.x;
  const int l = tid & 63, w = tid >> 6, g = l >> 4, l15 = l & 15;
  unsigned char* Plds = smem + 32768 + w * 4096;  // per-wave [32 q][64 k] bf16

  // bijective XCD swizzle: adjacent q-blocks (sharing K/V) land on the same XCD
  const int wg = ((blockIdx.x & 7) << 8) + (blockIdx.x >> 3);   // 2048 % 8 == 0
  const int n = wg & 63, h = (wg >> 6) & 15, b = wg >> 10;

  const float* Qp = Qg + (size_t)b * S * RS + h * 64;
  const float* Kp = Kg + (size_t)b * S * RS + h * 64;
  const float* Vp = Vg + (size_t)b * S * RS + h * 64;
  float*       Op = Og + (size_t)b * S * RS + h * 64;

  const int wq0 = 32 * w;            // wave's first q row within the 128-row block
  const int qg0 = n * 128 + wq0;

  // staging address components (constant across tiles)
  const int kr_ = tid >> 3, kch = tid & 7;          // K: row, 8-float chunk (cc adds 32 rows)
  const int vd = tid & 63, vkc0 = tid >> 6;         // V: d, k-chunk (cc adds 4)
  const int kvb = n * 128 - 256;                    // window base (row units)
  const int t0 = (n == 0) ? 4 : ((n == 1) ? 2 : 0); // skip tiles before row 0

  // ---- Q fragments in registers, pre-scaled by SCL2: q = 16*nr+l15, d = g*8+32*ks..+7
  short8 qf[2][2];
#pragma unroll
  for (int nr = 0; nr < 2; ++nr) {
    const float* qrow = Qp + (size_t)(qg0 + 16 * nr + l15) * RS;
#pragma unroll
    for (int ks = 0; ks < 2; ++ks) {
      float4 a = *(const float4*)(qrow + g * 8 + 32 * ks);
      float4 c = *(const float4*)(qrow + g * 8 + 32 * ks + 4);
      a.x *= SCL2; a.y *= SCL2; a.z *= SCL2; a.w *= SCL2;
      c.x *= SCL2; c.y *= SCL2; c.z *= SCL2; c.w *= SCL2;
      qf[ks][nr] = pk8(a, c);
    }
  }

  f32x4 acc[2][4];                   // [q-16-tile][d-16-tile]
#pragma unroll
  for (int i = 0; i < 2; ++i)
#pragma unroll
    for (int j = 0; j < 4; ++j) acc[i][j] = f32x4{0.f, 0.f, 0.f, 0.f};
  float m_run[2] = {-1e20f, -1e20f};
  float l_run[2] = {0.f, 0.f};

  // ---- T14 async-STAGE: issue global loads into regs (early), write LDS (late)
  auto issueT = [&](float4* kr, float* vr, int t) {
#pragma unroll
    for (int cc = 0; cc < 2; ++cc) {
      const float* ks_ = Kp + (size_t)(kvb + t * 64 + kr_ + 32 * cc) * RS + kch * 8;
      kr[2 * cc]     = *(const float4*)(ks_);
      kr[2 * cc + 1] = *(const float4*)(ks_ + 4);
      const float* vs = Vp + (size_t)(kvb + t * 64 + (vkc0 + 4 * cc) * 8) * RS + vd;
#pragma unroll
      for (int i = 0; i < 8; ++i) vr[8 * cc + i] = vs[(size_t)i * RS];
    }
  };
  auto writeT = [&](unsigned char* Kb, unsigned char* Vb, const float4* kr, const float* vr) {
#pragma unroll
    for (int cc = 0; cc < 2; ++cc) {
      int r = kr_ + 32 * cc;
      *(short8*)(Kb + r * 128 + ((kch ^ (r & 7)) << 4)) = pk8(kr[2 * cc], kr[2 * cc + 1]);
      int kc = vkc0 + 4 * cc;
      u32x4 u = { pk2(vr[8 * cc + 0], vr[8 * cc + 1]), pk2(vr[8 * cc + 2], vr[8 * cc + 3]),
                  pk2(vr[8 * cc + 4], vr[8 * cc + 5]), pk2(vr[8 * cc + 6], vr[8 * cc + 7]) };
      *(short8*)(Vb + vd * 128 + ((kc ^ (vd & 7)) << 4)) = __builtin_bit_cast(short8, u);
    }
  };

  auto computeT = [&](const unsigned char* Kb, const unsigned char* Vb, int t) {
    // wave-uniform activity: does [64t,64t+63] overlap (wq0, wq0+31+256] ?
    if (!(64 * t + 63 > wq0 && 64 * t <= wq0 + 287)) return;
    const bool noMask = (64 * t >= wq0 + 32) && (64 * t + 63 <= wq0 + 256);

    // ---- S^T = K·Q^T (rows k, cols q)
    f32x4 s[4][2];
#pragma unroll
    for (int i = 0; i < 4; ++i)
#pragma unroll
      for (int j = 0; j < 2; ++j) s[i][j] = f32x4{0.f, 0.f, 0.f, 0.f};
#pragma unroll
    for (int ks = 0; ks < 2; ++ks) {
      short8 kf[4];
#pragma unroll
      for (int mr = 0; mr < 4; ++mr) {
        int r = mr * 16 + l15;
        kf[mr] = *(const short8*)(Kb + r * 128 + (((g + 4 * ks) ^ (r & 7)) << 4));
      }
#pragma unroll
      for (int mr = 0; mr < 4; ++mr)
#pragma unroll
        for (int nr = 0; nr < 2; ++nr)
          s[mr][nr] = __builtin_amdgcn_mfma_f32_16x16x32_bf16(kf[mr], qf[ks][nr],
                                                              s[mr][nr], 0, 0, 0);
    }

    // ---- online softmax (log2 domain; scale already folded into Q)
    float corrv[2];
#pragma unroll
    for (int nr = 0; nr < 2; ++nr) {
      int q = wq0 + 16 * nr + l15;
      float mx = -3e38f;
      if (noMask) {
#pragma unroll
        for (int mr = 0; mr < 4; ++mr)
#pragma unroll
          for (int reg = 0; reg < 4; ++reg) mx = fmaxf(mx, s[mr][nr][reg]);
      } else {
#pragma unroll
        for (int mr = 0; mr < 4; ++mr)
#pragma unroll
          for (int reg = 0; reg < 4; ++reg) {
            int koff = 64 * t + 16 * mr + 4 * g + reg;
            bool valid = (koff > q) && (koff <= q + 256);
            float sv = valid ? s[mr][nr][reg] : -1e30f;
            s[mr][nr][reg] = sv;
            mx = fmaxf(mx, sv);
          }
      }
      mx = fmaxf(mx, __shfl_xor(mx, 16));
      mx = fmaxf(mx, __shfl_xor(mx, 32));
      float mnew = fmaxf(m_run[nr], mx);
      float corr = exp2f(m_run[nr] - mnew);
      m_run[nr] = mnew;
      float sum = 0.f;
#pragma unroll
      for (int mr = 0; mr < 4; ++mr)
#pragma unroll
        for (int reg = 0; reg < 4; ++reg) {
          float p = exp2f(s[mr][nr][reg] - mnew);
          s[mr][nr][reg] = p;
          sum += p;
        }
      sum += __shfl_xor(sum, 16);
      sum += __shfl_xor(sum, 32);
      l_run[nr] = l_run[nr] * corr + sum;
      corrv[nr] = corr;
    }
    // ---- P → per-wave LDS [32 q][64 k] bf16, swizzled (ends s's lifetime)
#pragma unroll
    for (int nr = 0; nr < 2; ++nr)
#pragma unroll
      for (int mr = 0; mr < 4; ++mr) {
        int q = 16 * nr + l15;
        int cb = 2 * mr + (g >> 1);
        int off = q * 128 + ((cb ^ (q & 7)) << 4) + ((g & 1) << 3);
        u32x2 pw = { pk2(s[mr][nr][0], s[mr][nr][1]),
                     pk2(s[mr][nr][2], s[mr][nr][3]) };
        *(u32x2*)(Plds + off) = pw;
      }
    // ---- rescale O while the P ds_writes drain
#pragma unroll
    for (int mq = 0; mq < 2; ++mq)
#pragma unroll
      for (int reg = 0; reg < 4; ++reg) {
        float c = __shfl(corrv[mq], 4 * g + reg, 16);
#pragma unroll
        for (int nd = 0; nd < 4; ++nd) acc[mq][nd][reg] *= c;
      }
    asm volatile("s_waitcnt lgkmcnt(0)" ::: "memory");  // within-wave cross-lane RAW

    // ---- O += P·V  (A rows = q, B rows = d, contiguous b128 reads)
#pragma unroll
    for (int ks = 0; ks < 2; ++ks) {
      short8 pf[2], vf[4];
#pragma unroll
      for (int mq = 0; mq < 2; ++mq) {
        int q = 16 * mq + l15;
        pf[mq] = *(const short8*)(Plds + q * 128 + (((g + 4 * ks) ^ (q & 7)) << 4));
      }
#pragma unroll
      for (int nd = 0; nd < 4; ++nd) {
        int d = 16 * nd + l15;
        vf[nd] = *(const short8*)(Vb + d * 128 + (((g + 4 * ks) ^ (d & 7)) << 4));
      }
#pragma unroll
      for (int mq = 0; mq < 2; ++mq)
#pragma unroll
        for (int nd = 0; nd < 4; ++nd)
          acc[mq][nd] = __builtin_amdgcn_mfma_f32_16x16x32_bf16(pf[mq], vf[nd],
                                                                acc[mq][nd], 0, 0, 0);
    }
  };

  // ---- main loop: pairs of tiles, named reg sets A (even) / B (odd)
  float4 krA[4]; float vrA[16];
  float4 krB[4]; float vrB[16];
  issueT(krA, vrA, t0);                       // prologue: first tile in flight

  for (int tp = t0 >> 1; tp < 3; ++tp) {
    const int te = 2 * tp;                    // even tile (regs A, buffers 0)
    writeT(Kb0, Vb0, krA, vrA);               // vmcnt drain happens here
    __syncthreads();
    issueT(krB, vrB, te + 1);                 // te+1 <= 5 always
    computeT(Kb0, Vb0, te);

    writeT(Kb1, Vb1, krB, vrB);               // odd tile (regs B, buffers 1)
    __syncthreads();
    if (te + 2 < 6) issueT(krA, vrA, te + 2);
    computeT(Kb1, Vb1, te + 1);
  }

  // ---- finalize
  float linv[2] = {1.0f / l_run[0], 1.0f / l_run[1]};
#pragma unroll
  for (int mq = 0; mq < 2; ++mq)
#pragma unroll
    for (int reg = 0; reg < 4; ++reg) {
      float li = __shfl(linv[mq], 4 * g + reg, 16);
      int qrow = qg0 + 16 * mq + 4 * g + reg;
      float* orow = Op + (size_t)qrow * RS;
#pragma unroll
      for (int nd = 0; nd < 4; ++nd)
        orow[16 * nd + l15] = acc[mq][nd][reg] * li;
    }
}

extern "C" void kernel_launch(void* const* d_in, const int* in_sizes, int n_in,
                              void* d_out, int out_size, void* d_ws, size_t ws_size,
                              hipStream_t stream) {
  (void)in_sizes; (void)n_in; (void)d_ws; (void)ws_size; (void)out_size;
  const float* q = (const float*)d_in[0];
  const float* k = (const float*)d_in[1];
  const float* v = (const float*)d_in[2];
  float* o = (float*)d_out;
  dim3 grid(2 * 16 * 64);   // B * H * (8192/128) = 2048 workgroups
  dim3 block(256);
  lattn<<<grid, block, 0, stream>>>(q, k, v, o);
}

// Round 9
// 832.602 us; speedup vs baseline: 1.0414x; 1.0414x over previous
//
#include <hip/hip_runtime.h>

typedef __attribute__((ext_vector_type(8))) short short8;
typedef __attribute__((ext_vector_type(4))) float f32x4;
typedef __attribute__((ext_vector_type(2))) unsigned u32x2;
typedef __attribute__((ext_vector_type(4))) unsigned u32x4;

#define SCL2 0.18033688011112042f   /* 64^-0.5 * log2(e), folded into Q */

__device__ __forceinline__ unsigned pk2(float lo, float hi) {
  unsigned r;
  asm("v_cvt_pk_bf16_f32 %0, %1, %2" : "=v"(r) : "v"(lo), "v"(hi));
  return r;
}

__device__ __forceinline__ short8 pk8(float4 a, float4 b) {
  u32x4 u = { pk2(a.x, a.y), pk2(a.z, a.w), pk2(b.x, b.y), pk2(b.z, b.w) };
  return __builtin_bit_cast(short8, u);
}

// Staging as MACROS on named local arrays (NOT lambda pointer params): pointer
// parameters take the array's address -> defeats SROA -> 2x32 dwords/thread in
// scratch -> 2.4 GB of HBM round-trip (measured round 7). Macro text keeps all
// indices compile-time so the arrays stay in VGPRs.
#define ISSUE_T(kr, vr, t)                                                        \
  do {                                                                            \
    _Pragma("unroll")                                                             \
    for (int cc = 0; cc < 2; ++cc) {                                              \
      const float* ks_ = Kp + (size_t)(kvb + (t) * 64 + kr_ + 32 * cc) * RS + kch * 8; \
      kr[2 * cc]     = *(const float4*)(ks_);                                     \
      kr[2 * cc + 1] = *(const float4*)(ks_ + 4);                                 \
      const float* vs_ = Vp + (size_t)(kvb + (t) * 64 + (vkc0 + 4 * cc) * 8) * RS + vd; \
      _Pragma("unroll")                                                           \
      for (int i = 0; i < 8; ++i) vr[8 * cc + i] = vs_[(size_t)i * RS];           \
    }                                                                             \
  } while (0)

#define WRITE_T(Kb, Vb, kr, vr)                                                   \
  do {                                                                            \
    _Pragma("unroll")                                                             \
    for (int cc = 0; cc < 2; ++cc) {                                              \
      int r_ = kr_ + 32 * cc;                                                     \
      *(short8*)((Kb) + r_ * 128 + ((kch ^ (r_ & 7)) << 4)) =                     \
          pk8(kr[2 * cc], kr[2 * cc + 1]);                                        \
      int kc_ = vkc0 + 4 * cc;                                                    \
      u32x4 u_ = { pk2(vr[8 * cc + 0], vr[8 * cc + 1]),                           \
                   pk2(vr[8 * cc + 2], vr[8 * cc + 3]),                           \
                   pk2(vr[8 * cc + 4], vr[8 * cc + 5]),                           \
                   pk2(vr[8 * cc + 6], vr[8 * cc + 7]) };                         \
      *(short8*)((Vb) + vd * 128 + ((kc_ ^ (vd & 7)) << 4)) =                     \
          __builtin_bit_cast(short8, u_);                                         \
    }                                                                             \
  } while (0)

__global__ __launch_bounds__(256, 3)   // 3 waves/EU -> ~170 unified regs/wave
void lattn(const float* __restrict__ Qg, const float* __restrict__ Kg,
           const float* __restrict__ Vg, float* __restrict__ Og) {
  constexpr int S = 8192, H = 16, RS = H * 64;   // row stride in floats
  __shared__ __align__(16) unsigned char smem[49152];
  unsigned char* Kb0 = smem;             // double-buffered K/V tiles (8 KB each)
  unsigned char* Vb0 = smem + 8192;
  unsigned char* Kb1 = smem + 16384;
  unsigned char* Vb1 = smem + 24576;

  const int tid = threadIdx.x;
  const int l = tid & 63, w = tid >> 6, g = l >> 4, l15 = l & 15;
  unsigned char* Plds = smem + 32768 + w * 4096;  // per-wave [32 q][64 k] bf16

  // bijective XCD swizzle: adjacent q-blocks (sharing K/V) land on the same XCD
  const int wg = ((blockIdx.x & 7) << 8) + (blockIdx.x >> 3);   // 2048 % 8 == 0
  const int n = wg & 63, h = (wg >> 6) & 15, b = wg >> 10;

  const float* Qp = Qg + (size_t)b * S * RS + h * 64;
  const float* Kp = Kg + (size_t)b * S * RS + h * 64;
  const float* Vp = Vg + (size_t)b * S * RS + h * 64;
  float*       Op = Og + (size_t)b * S * RS + h * 64;

  const int wq0 = 32 * w;            // wave's first q row within the 128-row block
  const int qg0 = n * 128 + wq0;

  // staging address components (constant across tiles)
  const int kr_ = tid >> 3, kch = tid & 7;          // K: row, 8-float chunk
  const int vd = tid & 63, vkc0 = tid >> 6;         // V: d, k-chunk
  const int kvb = n * 128 - 256;                    // window base (row units)
  const int t0 = (n == 0) ? 4 : ((n == 1) ? 2 : 0); // skip tiles before row 0

  // ---- Q fragments in registers, pre-scaled by SCL2: q = 16*nr+l15, d = g*8+32*ks..+7
  short8 qf[2][2];
#pragma unroll
  for (int nr = 0; nr < 2; ++nr) {
    const float* qrow = Qp + (size_t)(qg0 + 16 * nr + l15) * RS;
#pragma unroll
    for (int ks = 0; ks < 2; ++ks) {
      float4 a = *(const float4*)(qrow + g * 8 + 32 * ks);
      float4 c = *(const float4*)(qrow + g * 8 + 32 * ks + 4);
      a.x *= SCL2; a.y *= SCL2; a.z *= SCL2; a.w *= SCL2;
      c.x *= SCL2; c.y *= SCL2; c.z *= SCL2; c.w *= SCL2;
      qf[ks][nr] = pk8(a, c);
    }
  }

  f32x4 acc[2][4];                   // [q-16-tile][d-16-tile]
#pragma unroll
  for (int i = 0; i < 2; ++i)
#pragma unroll
    for (int j = 0; j < 4; ++j) acc[i][j] = f32x4{0.f, 0.f, 0.f, 0.f};
  float m_run[2] = {-1e20f, -1e20f};
  float l_run[2] = {0.f, 0.f};

  auto computeT = [&](const unsigned char* Kb, const unsigned char* Vb, int t) {
    // wave-uniform activity: does [64t,64t+63] overlap (wq0, wq0+31+256] ?
    if (!(64 * t + 63 > wq0 && 64 * t <= wq0 + 287)) return;
    const bool noMask = (64 * t >= wq0 + 32) && (64 * t + 63 <= wq0 + 256);

    // ---- S^T = K·Q^T (rows k, cols q)
    f32x4 s[4][2];
#pragma unroll
    for (int i = 0; i < 4; ++i)
#pragma unroll
      for (int j = 0; j < 2; ++j) s[i][j] = f32x4{0.f, 0.f, 0.f, 0.f};
#pragma unroll
    for (int ks = 0; ks < 2; ++ks) {
      short8 kf[4];
#pragma unroll
      for (int mr = 0; mr < 4; ++mr) {
        int r = mr * 16 + l15;
        kf[mr] = *(const short8*)(Kb + r * 128 + (((g + 4 * ks) ^ (r & 7)) << 4));
      }
#pragma unroll
      for (int mr = 0; mr < 4; ++mr)
#pragma unroll
        for (int nr = 0; nr < 2; ++nr)
          s[mr][nr] = __builtin_amdgcn_mfma_f32_16x16x32_bf16(kf[mr], qf[ks][nr],
                                                              s[mr][nr], 0, 0, 0);
    }

    // ---- online softmax (log2 domain; scale already folded into Q)
    float corrv[2];
#pragma unroll
    for (int nr = 0; nr < 2; ++nr) {
      int q = wq0 + 16 * nr + l15;
      float mx = -3e38f;
      if (noMask) {
#pragma unroll
        for (int mr = 0; mr < 4; ++mr)
#pragma unroll
          for (int reg = 0; reg < 4; ++reg) mx = fmaxf(mx, s[mr][nr][reg]);
      } else {
#pragma unroll
        for (int mr = 0; mr < 4; ++mr)
#pragma unroll
          for (int reg = 0; reg < 4; ++reg) {
            int koff = 64 * t + 16 * mr + 4 * g + reg;
            bool valid = (koff > q) && (koff <= q + 256);
            float sv = valid ? s[mr][nr][reg] : -1e30f;
            s[mr][nr][reg] = sv;
            mx = fmaxf(mx, sv);
          }
      }
      mx = fmaxf(mx, __shfl_xor(mx, 16));
      mx = fmaxf(mx, __shfl_xor(mx, 32));
      float mnew = fmaxf(m_run[nr], mx);
      float corr = exp2f(m_run[nr] - mnew);
      m_run[nr] = mnew;
      float sum = 0.f;
#pragma unroll
      for (int mr = 0; mr < 4; ++mr)
#pragma unroll
        for (int reg = 0; reg < 4; ++reg) {
          float p = exp2f(s[mr][nr][reg] - mnew);
          s[mr][nr][reg] = p;
          sum += p;
        }
      sum += __shfl_xor(sum, 16);
      sum += __shfl_xor(sum, 32);
      l_run[nr] = l_run[nr] * corr + sum;
      corrv[nr] = corr;
    }
    // ---- P → per-wave LDS [32 q][64 k] bf16, swizzled (ends s's lifetime)
#pragma unroll
    for (int nr = 0; nr < 2; ++nr)
#pragma unroll
      for (int mr = 0; mr < 4; ++mr) {
        int q = 16 * nr + l15;
        int cb = 2 * mr + (g >> 1);
        int off = q * 128 + ((cb ^ (q & 7)) << 4) + ((g & 1) << 3);
        u32x2 pw = { pk2(s[mr][nr][0], s[mr][nr][1]),
                     pk2(s[mr][nr][2], s[mr][nr][3]) };
        *(u32x2*)(Plds + off) = pw;
      }
    // ---- rescale O while the P ds_writes drain
#pragma unroll
    for (int mq = 0; mq < 2; ++mq)
#pragma unroll
      for (int reg = 0; reg < 4; ++reg) {
        float c = __shfl(corrv[mq], 4 * g + reg, 16);
#pragma unroll
        for (int nd = 0; nd < 4; ++nd) acc[mq][nd][reg] *= c;
      }
    asm volatile("s_waitcnt lgkmcnt(0)" ::: "memory");  // within-wave cross-lane RAW

    // ---- O += P·V  (A rows = q, B rows = d, contiguous b128 reads)
#pragma unroll
    for (int ks = 0; ks < 2; ++ks) {
      short8 pf[2], vf[4];
#pragma unroll
      for (int mq = 0; mq < 2; ++mq) {
        int q = 16 * mq + l15;
        pf[mq] = *(const short8*)(Plds + q * 128 + (((g + 4 * ks) ^ (q & 7)) << 4));
      }
#pragma unroll
      for (int nd = 0; nd < 4; ++nd) {
        int d = 16 * nd + l15;
        vf[nd] = *(const short8*)(Vb + d * 128 + (((g + 4 * ks) ^ (d & 7)) << 4));
      }
#pragma unroll
      for (int mq = 0; mq < 2; ++mq)
#pragma unroll
        for (int nd = 0; nd < 4; ++nd)
          acc[mq][nd] = __builtin_amdgcn_mfma_f32_16x16x32_bf16(pf[mq], vf[nd],
                                                                acc[mq][nd], 0, 0, 0);
    }
  };

  // ---- main loop: pairs of tiles, named reg sets A (even tile) / B (odd tile)
  float4 krA[4]; float vrA[16];
  float4 krB[4]; float vrB[16];
  ISSUE_T(krA, vrA, t0);                      // prologue: first tile in flight

  for (int tp = t0 >> 1; tp < 3; ++tp) {
    const int te = 2 * tp;
    WRITE_T(Kb0, Vb0, krA, vrA);              // waits vmcnt for A internally
    __syncthreads();
    ISSUE_T(krB, vrB, te + 1);                // next tile's HBM latency hides under compute
    computeT(Kb0, Vb0, te);

    WRITE_T(Kb1, Vb1, krB, vrB);
    __syncthreads();
    if (te + 2 < 6) ISSUE_T(krA, vrA, te + 2);
    computeT(Kb1, Vb1, te + 1);
  }

  // ---- finalize
  float linv[2] = {1.0f / l_run[0], 1.0f / l_run[1]};
#pragma unroll
  for (int mq = 0; mq < 2; ++mq)
#pragma unroll
    for (int reg = 0; reg < 4; ++reg) {
      float li = __shfl(linv[mq], 4 * g + reg, 16);
      int qrow = qg0 + 16 * mq + 4 * g + reg;
      float* orow = Op + (size_t)qrow * RS;
#pragma unroll
      for (int nd = 0; nd < 4; ++nd)
        orow[16 * nd + l15] = acc[mq][nd][reg] * li;
    }
}

extern "C" void kernel_launch(void* const* d_in, const int* in_sizes, int n_in,
                              void* d_out, int out_size, void* d_ws, size_t ws_size,
                              hipStream_t stream) {
  (void)in_sizes; (void)n_in; (void)d_ws; (void)ws_size; (void)out_size;
  const float* q = (const float*)d_in[0];
  const float* k = (const float*)d_in[1];
  const float* v = (const float*)d_in[2];
  float* o = (float*)d_out;
  dim3 grid(2 * 16 * 64);   // B * H * (8192/128) = 2048 workgroups
  dim3 block(256);
  lattn<<<grid, block, 0, stream>>>(q, k, v, o);
}

// Round 10
// 257.682 us; speedup vs baseline: 3.3648x; 3.2311x over previous
//
#include <hip/hip_runtime.h>

typedef __attribute__((ext_vector_type(8))) short short8;
typedef __attribute__((ext_vector_type(4))) float f32x4;
typedef __attribute__((ext_vector_type(2))) unsigned u32x2;
typedef __attribute__((ext_vector_type(4))) unsigned u32x4;

#define SCL2 0.18033688011112042f   /* 64^-0.5 * log2(e), folded into Q */

__device__ __forceinline__ unsigned pk2(float lo, float hi) {
  unsigned r;
  asm("v_cvt_pk_bf16_f32 %0, %1, %2" : "=v"(r) : "v"(lo), "v"(hi));
  return r;
}

__device__ __forceinline__ short8 pk8(float4 a, float4 b) {
  u32x4 u = { pk2(a.x, a.y), pk2(a.z, a.w), pk2(b.x, b.y), pk2(b.z, b.w) };
  return __builtin_bit_cast(short8, u);
}

// LDS-visibility barrier that does NOT drain vmcnt: global prefetch loads stay
// in flight across it (unlike __syncthreads, which emits s_waitcnt vmcnt(0)).
#define LDS_BARRIER()                                        \
  do {                                                       \
    asm volatile("s_waitcnt lgkmcnt(0)" ::: "memory");       \
    __builtin_amdgcn_sched_barrier(0);                       \
    __builtin_amdgcn_s_barrier();                            \
    __builtin_amdgcn_sched_barrier(0);                       \
  } while (0)

__global__ __launch_bounds__(256, 3)   // 3 waves/EU -> ~170 unified regs/wave
void lattn(const float* __restrict__ Qg, const float* __restrict__ Kg,
           const float* __restrict__ Vg, float* __restrict__ Og) {
  constexpr int S = 8192, H = 16, RS = H * 64;   // row stride in floats
  __shared__ __align__(16) unsigned char smem[32768];
  unsigned char* Klds = smem;            // [64 k][64 d] bf16, swizzled (8 KB)
  unsigned char* Vlds = smem + 8192;     // [64 d][64 k] bf16 transposed (8 KB)

  const int tid = threadIdx.x;
  const int l = tid & 63, w = tid >> 6, g = l >> 4, l15 = l & 15;
  unsigned char* Plds = smem + 16384 + w * 4096;  // per-wave [32 q][64 k] bf16

  // bijective XCD swizzle: adjacent q-blocks (sharing K/V) land on the same XCD
  const int wg = ((blockIdx.x & 7) << 8) + (blockIdx.x >> 3);   // 2048 % 8 == 0
  const int n = wg & 63, h = (wg >> 6) & 15, b = wg >> 10;

  const float* Qp = Qg + (size_t)b * S * RS + h * 64;
  const float* Kp = Kg + (size_t)b * S * RS + h * 64;
  const float* Vp = Vg + (size_t)b * S * RS + h * 64;
  float*       Op = Og + (size_t)b * S * RS + h * 64;

  const int wq0 = 32 * w;            // wave's first q row within the 128-row block
  const int qg0 = n * 128 + wq0;

  // staging address components (constant across tiles)
  const int kr_ = tid >> 3, kch = tid & 7;          // K: row, 8-float chunk
  const int vd = tid & 63, vkc0 = tid >> 6;         // V: d, k-chunk
  const int kvb = n * 128 - 256;                    // window base (row units)
  const int t0 = (n == 0) ? 4 : ((n == 1) ? 2 : 0); // skip tiles before row 0

  // ---- Q fragments in registers, pre-scaled by SCL2: q = 16*nr+l15, d = g*8+32*ks..+7
  short8 qf[2][2];
#pragma unroll
  for (int nr = 0; nr < 2; ++nr) {
    const float* qrow = Qp + (size_t)(qg0 + 16 * nr + l15) * RS;
#pragma unroll
    for (int ks = 0; ks < 2; ++ks) {
      float4 a = *(const float4*)(qrow + g * 8 + 32 * ks);
      float4 c = *(const float4*)(qrow + g * 8 + 32 * ks + 4);
      a.x *= SCL2; a.y *= SCL2; a.z *= SCL2; a.w *= SCL2;
      c.x *= SCL2; c.y *= SCL2; c.z *= SCL2; c.w *= SCL2;
      qf[ks][nr] = pk8(a, c);
    }
  }

  f32x4 acc[2][4];                   // [q-16-tile][d-16-tile]
#pragma unroll
  for (int i = 0; i < 2; ++i)
#pragma unroll
    for (int j = 0; j < 4; ++j) acc[i][j] = f32x4{0.f, 0.f, 0.f, 0.f};
  float m_run[2] = {-1e20f, -1e20f};
  float l_run[2] = {0.f, 0.f};

  // ---- prologue: K(t0) prefetch into named registers (4 loads in flight)
  const float* kb0 = Kp + (size_t)(kvb + t0 * 64 + kr_) * RS + kch * 8;
  float4 kc0 = *(const float4*)(kb0);
  float4 kc1 = *(const float4*)(kb0 + 4);
  float4 kc2 = *(const float4*)(kb0 + (size_t)32 * RS);
  float4 kc3 = *(const float4*)(kb0 + (size_t)32 * RS + 4);
  float4 kn0 = kc0, kn1 = kc1, kn2 = kc2, kn3 = kc3;

  for (int t = t0; t < 6; ++t) {
    // ---- 1) issue V(t) loads into named scalars (in flight through QK+softmax)
    const float* vb0 = Vp + (size_t)(kvb + t * 64 + vkc0 * 8) * RS + vd;
    const float* vb1 = vb0 + (size_t)32 * RS;
    float vv0 = vb0[0],              vv1 = vb0[(size_t)1 * RS];
    float vv2 = vb0[(size_t)2 * RS], vv3 = vb0[(size_t)3 * RS];
    float vv4 = vb0[(size_t)4 * RS], vv5 = vb0[(size_t)5 * RS];
    float vv6 = vb0[(size_t)6 * RS], vv7 = vb0[(size_t)7 * RS];
    float vv8 = vb1[0],              vv9 = vb1[(size_t)1 * RS];
    float vvA = vb1[(size_t)2 * RS], vvB = vb1[(size_t)3 * RS];
    float vvC = vb1[(size_t)4 * RS], vvD = vb1[(size_t)5 * RS];
    float vvE = vb1[(size_t)6 * RS], vvF = vb1[(size_t)7 * RS];

    // ---- 2) pack + write K(t) -> LDS (auto-wait vmcnt(16): K done, V flying)
    {
      int r0 = kr_, r1 = kr_ + 32;
      *(short8*)(Klds + r0 * 128 + ((kch ^ (r0 & 7)) << 4)) = pk8(kc0, kc1);
      *(short8*)(Klds + r1 * 128 + ((kch ^ (r1 & 7)) << 4)) = pk8(kc2, kc3);
    }
    // ---- 3) K visible to all waves; V + K-next loads NOT drained
    LDS_BARRIER();

    // ---- 4) issue K(t+1) prefetch (uniform branch; stays in flight into next tile)
    if (t < 5) {
      const float* kb = Kp + (size_t)(kvb + (t + 1) * 64 + kr_) * RS + kch * 8;
      kn0 = *(const float4*)(kb);
      kn1 = *(const float4*)(kb + 4);
      kn2 = *(const float4*)(kb + (size_t)32 * RS);
      kn3 = *(const float4*)(kb + (size_t)32 * RS + 4);
    }

    // wave-uniform activity: does [64t,64t+63] overlap (wq0, wq0+31+256] ?
    const bool active = (64 * t + 63 > wq0) && (64 * t <= wq0 + 287);
    if (active) {
      const bool noMask = (64 * t >= wq0 + 32) && (64 * t + 63 <= wq0 + 256);

      // ---- S^T = K·Q^T (rows k, cols q)
      f32x4 s[4][2];
#pragma unroll
      for (int i = 0; i < 4; ++i)
#pragma unroll
        for (int j = 0; j < 2; ++j) s[i][j] = f32x4{0.f, 0.f, 0.f, 0.f};
#pragma unroll
      for (int ks = 0; ks < 2; ++ks) {
        short8 kf[4];
#pragma unroll
        for (int mr = 0; mr < 4; ++mr) {
          int r = mr * 16 + l15;
          kf[mr] = *(const short8*)(Klds + r * 128 + (((g + 4 * ks) ^ (r & 7)) << 4));
        }
#pragma unroll
        for (int mr = 0; mr < 4; ++mr)
#pragma unroll
          for (int nr = 0; nr < 2; ++nr)
            s[mr][nr] = __builtin_amdgcn_mfma_f32_16x16x32_bf16(kf[mr], qf[ks][nr],
                                                                s[mr][nr], 0, 0, 0);
      }

      // ---- online softmax (log2 domain; scale already folded into Q)
      float corrv[2];
#pragma unroll
      for (int nr = 0; nr < 2; ++nr) {
        int q = wq0 + 16 * nr + l15;
        float mx = -3e38f;
        if (noMask) {
#pragma unroll
          for (int mr = 0; mr < 4; ++mr)
#pragma unroll
            for (int reg = 0; reg < 4; ++reg) mx = fmaxf(mx, s[mr][nr][reg]);
        } else {
#pragma unroll
          for (int mr = 0; mr < 4; ++mr)
#pragma unroll
            for (int reg = 0; reg < 4; ++reg) {
              int koff = 64 * t + 16 * mr + 4 * g + reg;
              bool valid = (koff > q) && (koff <= q + 256);
              float sv = valid ? s[mr][nr][reg] : -1e30f;
              s[mr][nr][reg] = sv;
              mx = fmaxf(mx, sv);
            }
        }
        mx = fmaxf(mx, __shfl_xor(mx, 16));
        mx = fmaxf(mx, __shfl_xor(mx, 32));
        float mnew = fmaxf(m_run[nr], mx);
        float corr = exp2f(m_run[nr] - mnew);
        m_run[nr] = mnew;
        float sum = 0.f;
#pragma unroll
        for (int mr = 0; mr < 4; ++mr)
#pragma unroll
          for (int reg = 0; reg < 4; ++reg) {
            float p = exp2f(s[mr][nr][reg] - mnew);
            s[mr][nr][reg] = p;
            sum += p;
          }
        sum += __shfl_xor(sum, 16);
        sum += __shfl_xor(sum, 32);
        l_run[nr] = l_run[nr] * corr + sum;
        corrv[nr] = corr;
      }
      // ---- P -> per-wave LDS [32 q][64 k] bf16, swizzled
#pragma unroll
      for (int nr = 0; nr < 2; ++nr)
#pragma unroll
        for (int mr = 0; mr < 4; ++mr) {
          int q = 16 * nr + l15;
          int cb = 2 * mr + (g >> 1);
          int off = q * 128 + ((cb ^ (q & 7)) << 4) + ((g & 1) << 3);
          u32x2 pw = { pk2(s[mr][nr][0], s[mr][nr][1]),
                       pk2(s[mr][nr][2], s[mr][nr][3]) };
          *(u32x2*)(Plds + off) = pw;
        }
      // ---- rescale O while P ds_writes drain
#pragma unroll
      for (int mq = 0; mq < 2; ++mq)
#pragma unroll
        for (int reg = 0; reg < 4; ++reg) {
          float c = __shfl(corrv[mq], 4 * g + reg, 16);
#pragma unroll
          for (int nd = 0; nd < 4; ++nd) acc[mq][nd][reg] *= c;
        }
    }

    // ---- 6) pack + write V(t) -> LDS (auto-wait vmcnt(4): V done, K-next flying)
    {
      u32x4 u0 = { pk2(vv0, vv1), pk2(vv2, vv3), pk2(vv4, vv5), pk2(vv6, vv7) };
      int kc_ = vkc0;
      *(short8*)(Vlds + vd * 128 + ((kc_ ^ (vd & 7)) << 4)) = __builtin_bit_cast(short8, u0);
      u32x4 u1 = { pk2(vv8, vv9), pk2(vvA, vvB), pk2(vvC, vvD), pk2(vvE, vvF) };
      kc_ = vkc0 + 4;
      *(short8*)(Vlds + vd * 128 + ((kc_ ^ (vd & 7)) << 4)) = __builtin_bit_cast(short8, u1);
    }
    // ---- 7) V (and P) visible; K-next still in flight
    LDS_BARRIER();

    // ---- 8) O += P·V  (A rows = q, B rows = d, contiguous b128 reads)
    if (active) {
#pragma unroll
      for (int ks = 0; ks < 2; ++ks) {
        short8 pf[2], vf[4];
#pragma unroll
        for (int mq = 0; mq < 2; ++mq) {
          int q = 16 * mq + l15;
          pf[mq] = *(const short8*)(Plds + q * 128 + (((g + 4 * ks) ^ (q & 7)) << 4));
        }
#pragma unroll
        for (int nd = 0; nd < 4; ++nd) {
          int d = 16 * nd + l15;
          vf[nd] = *(const short8*)(Vlds + d * 128 + (((g + 4 * ks) ^ (d & 7)) << 4));
        }
#pragma unroll
        for (int mq = 0; mq < 2; ++mq)
#pragma unroll
          for (int nd = 0; nd < 4; ++nd)
            acc[mq][nd] = __builtin_amdgcn_mfma_f32_16x16x32_bf16(pf[mq], vf[nd],
                                                                  acc[mq][nd], 0, 0, 0);
      }
    }
    // ---- rotate K prefetch registers (named, no arrays)
    kc0 = kn0; kc1 = kn1; kc2 = kn2; kc3 = kn3;
    // next tile's K-write happens after this barrier-separated region; Klds
    // readers (QK, pre-barrier-1) and writer (step 2) never overlap.
  }

  // ---- finalize
  float linv[2] = {1.0f / l_run[0], 1.0f / l_run[1]};
#pragma unroll
  for (int mq = 0; mq < 2; ++mq)
#pragma unroll
    for (int reg = 0; reg < 4; ++reg) {
      float li = __shfl(linv[mq], 4 * g + reg, 16);
      int qrow = qg0 + 16 * mq + 4 * g + reg;
      float* orow = Op + (size_t)qrow * RS;
#pragma unroll
      for (int nd = 0; nd < 4; ++nd)
        orow[16 * nd + l15] = acc[mq][nd][reg] * li;
    }
}

extern "C" void kernel_launch(void* const* d_in, const int* in_sizes, int n_in,
                              void* d_out, int out_size, void* d_ws, size_t ws_size,
                              hipStream_t stream) {
  (void)in_sizes; (void)n_in; (void)d_ws; (void)ws_size; (void)out_size;
  const float* q = (const float*)d_in[0];
  const float* k = (const float*)d_in[1];
  const float* v = (const float*)d_in[2];
  float* o = (float*)d_out;
  dim3 grid(2 * 16 * 64);   // B * H * (8192/128) = 2048 workgroups
  dim3 block(256);
  lattn<<<grid, block, 0, stream>>>(q, k, v, o);
}